// Round 19
// baseline (250.633 us; speedup 1.0000x reference)
//
#include <hip/hip_runtime.h>
#include <hip/hip_bf16.h>

#define NPTS 262144
#define DIM  128
#define KC   20
#define MP   10
#define LNEPS 1e-5f
#define EPSI  0.05f
#define CCAP  65536

typedef _Float16 half8 __attribute__((ext_vector_type(8)));
typedef float f32x4 __attribute__((ext_vector_type(4)));
typedef float fv4 __attribute__((ext_vector_type(4)));

union H8U4 { half8 h; uint4 u; };

// workspace layout (float offsets)
#define WS_PN     0          // 25600 normalized protos f32
#define WS_PHI    25600      // 14336 floats (224x128 f16 hi, PRE-SWIZZLED, rows 200..223 zero)
#define WS_PLO    39936      // 14336 floats (f16 lo, PRE-SWIZZLED)
#define WS_F      54272      // 25600 f accumulator
#define WS_NCOUNT 79872      // 200
#define WS_CCNT   80072      // 8 ints (ccnt + pad)
#define WS_UH     80080      // 600 u history (3 x 200)
#define WS_CS     80680      // 224 column sums (0..199 e-sums, 200..219 counts)
#define WS_PCB    80904      // 2048*224 per-block partials (coalesced); pr aliases
#define WS_EXPV   998408     // N*10 packed
#define WS_CIDX   3619848    // 65536 ints
// total 3685384 floats = 14.7 MB

#define EPIT 212   // epilogue LDS pitch (16B-aligned rows)

#define MFMA_(b_, a_, c_) __builtin_amdgcn_mfma_f32_16x16x32_f16(b_, a_, c_, 0, 0, 0)

__device__ __forceinline__ half8 lds_h8(const uint4* p) {
    return *reinterpret_cast<const half8*>(p);
}

// async global->LDS, 16B per lane; LDS dest = wave-uniform base + lane*16
__device__ __forceinline__ void gload_lds16(const uint4* g, uint4* l) {
    __builtin_amdgcn_global_load_lds(
        (const __attribute__((address_space(1))) void*)(g),
        (__attribute__((address_space(3))) void*)(l), 16, 0, 0);
}

// nontemporal float4 store (final outputs: skip L2 retention)
__device__ __forceinline__ void nt_store4(float* p, float x, float y, float z, float w) {
    fv4 v = {x, y, z, w};
    __builtin_nontemporal_store(v, (fv4*)p);
}

// u1 / S from colsum — pure function, identical everywhere (left-assoc order)
__device__ __forceinline__ float class_S(const float* cs, int k) {
    float S = 0.f;
    #pragma unroll
    for (int m = 0; m < 10; ++m) S += cs[k*10 + m];
    return S;
}
__device__ __forceinline__ float u1_of(const float* cs, int j) {
    int k = j / 10;
    float S = class_S(cs, k);
    float r1 = (S > 0.f) ? cs[j] / S : cs[j];
    return (r1 > 0.f) ? 1.f/(10.f*r1) : 0.1f;
}

// ---- normalize prototypes; emit f32 (pn) + PRE-SWIZZLED f16 hi/lo.
//  Also zeroes the facc/ncount/ccnt region (folds the memset launch).
__global__ __launch_bounds__(64) void k_norm_protos(
    const float* __restrict__ pr, float* __restrict__ pn,
    _Float16* __restrict__ phi, _Float16* __restrict__ plo,
    float* __restrict__ zbuf)
{
    int j = blockIdx.x, l = threadIdx.x;
    {   // grid-stride zero of facc(25600)+ncnt(200)+ccnt(8) = 25808 floats
        int tid = j*64 + l;
        for (int i = tid; i < 25808; i += 14336) zbuf[i] = 0.f;
    }
    const int jm = j & 15;
    const int s1 = l >> 3,       swz1 = (((s1 ^ jm) << 3) | (l & 7));
    const int s2 = 8 + (l >> 3), swz2 = (((s2 ^ jm) << 3) | (l & 7));
    if (j < 200) {
        float x0 = pr[(size_t)j*128 + l], x1 = pr[(size_t)j*128 + 64 + l];
        float ss = x0*x0 + x1*x1;
        #pragma unroll
        for (int off = 32; off > 0; off >>= 1) ss += __shfl_xor(ss, off);
        float dn = fmaxf(sqrtf(ss), 1e-12f);
        float y0 = x0/dn, y1 = x1/dn;
        pn[(size_t)j*128 + l]      = y0;
        pn[(size_t)j*128 + 64 + l] = y1;
        _Float16 h0 = (_Float16)y0, h1 = (_Float16)y1;
        phi[(size_t)j*128 + swz1] = h0;
        phi[(size_t)j*128 + swz2] = h1;
        plo[(size_t)j*128 + swz1] = (_Float16)(y0 - (float)h0);
        plo[(size_t)j*128 + swz2] = (_Float16)(y1 - (float)h1);
    } else {
        phi[(size_t)j*128 + swz1] = (_Float16)0.f;  phi[(size_t)j*128 + swz2] = (_Float16)0.f;
        plo[(size_t)j*128 + swz1] = (_Float16)0.f;  plo[(size_t)j*128 + swz2] = (_Float16)0.f;
    }
}

// ---- main kernel: 2048 blocks x 256 thr (4 waves), 2 chunks of 64 pts each.
//  Chunk 1's A-loads and B0/B1 stages are issued during chunk 0's epilogue
//  (dead LDS/register regions), hiding their latency entirely.
__global__ __launch_bounds__(256, 3) void k_main(
    const float* __restrict__ feat, const int* __restrict__ gt,
    const _Float16* __restrict__ phi, const _Float16* __restrict__ plo,
    const float* __restrict__ fg, const float* __restrict__ fb,
    const float* __restrict__ mg, const float* __restrict__ mb,
    float* __restrict__ out_seg, float* __restrict__ plog,
    float* __restrict__ expv, float* __restrict__ pcb,
    int* __restrict__ cidx, int* __restrict__ ccnt)
{
    __shared__ __align__(16) char ldsb[32768];
    uint4* bbuf = (uint4*)ldsb;                  // 2 bufs x 1024 u4; GEMM phase
    float* epi  = (float*)ldsb;                  // [32][EPIT] = 27136 B; epilogue phase
    float* osg  = (float*)(ldsb + 27136);        // [32][20] = 2560 B
    float* exs  = (float*)(ldsb + 29696);        // [32][10] = 1280 B
    int*   gtS  = (int*)  (ldsb + 30976);        // 64 ints
    float* part = (float*)(ldsb + 31232);        // 160 floats
    float* cntS = (float*)(ldsb + 31872);        // 20 floats -> ends 31952

    const int t = threadIdx.x, blk = blockIdx.x;
    const int w = t >> 6, lane = t & 63;
    const int l15 = lane & 15, l4 = lane >> 4;

    const uint4* phi4 = (const uint4*)phi;
    const uint4* plo4 = (const uint4*)plo;
    const float4* gfeat = (const float4*)feat;

#define STAGE_B(S, BI) do { \
        const uint4* gh = phi4 + (size_t)(S)*512 + t; \
        const uint4* gl = plo4 + (size_t)(S)*512 + t; \
        uint4* dh = bbuf + (BI)*1024 + w*64; \
        uint4* dl = bbuf + (BI)*1024 + 512 + w*64; \
        gload_lds16(gh,       dh); \
        gload_lds16(gh + 256, dh + 256); \
        gload_lds16(gl,       dl); \
        gload_lds16(gl + 256, dl + 256); \
    } while (0)

#define ALOAD(PB) do { \
        size_t rb = (size_t)((PB) + w*16 + l15) * 32; \
        _Pragma("unroll") \
        for (int kst = 0; kst < 4; ++kst) \
            _Pragma("unroll") \
            for (int h = 0; h < 2; ++h) \
                A[kst][h] = gfeat[rb + kst*8 + l4*2 + h]; \
    } while (0)

// LN + l2n on A (4-lane group reduce over lanes {l15,+16,+32,+48}) -> fah/fal
#define LN_BODY do { \
        const float4* fg4 = (const float4*)fg; \
        const float4* fb4 = (const float4*)fb; \
        float4 G[4][2], Bb[4][2]; \
        _Pragma("unroll") \
        for (int kst = 0; kst < 4; ++kst) \
            _Pragma("unroll") \
            for (int h = 0; h < 2; ++h) { \
                G[kst][h]  = fg4[kst*8 + l4*2 + h]; \
                Bb[kst][h] = fb4[kst*8 + l4*2 + h]; \
            } \
        float s0 = 0.f; \
        _Pragma("unroll") \
        for (int kst = 0; kst < 4; ++kst) \
            _Pragma("unroll") \
            for (int h = 0; h < 2; ++h) { \
                float4 v = A[kst][h]; \
                s0 += v.x + v.y + v.z + v.w; \
            } \
        s0 += __shfl_xor(s0, 16); s0 += __shfl_xor(s0, 32); \
        float mean = s0 * (1.f/128.f); \
        float s1 = 0.f; \
        _Pragma("unroll") \
        for (int kst = 0; kst < 4; ++kst) \
            _Pragma("unroll") \
            for (int h = 0; h < 2; ++h) { \
                float4 v = A[kst][h]; \
                float a = v.x-mean, b = v.y-mean, c = v.z-mean, d = v.w-mean; \
                s1 += a*a + b*b + c*c + d*d; \
            } \
        s1 += __shfl_xor(s1, 16); s1 += __shfl_xor(s1, 32); \
        float rstd = rsqrtf(s1 * (1.f/128.f) + LNEPS); \
        float s2 = 0.f; \
        _Pragma("unroll") \
        for (int kst = 0; kst < 4; ++kst) \
            _Pragma("unroll") \
            for (int h = 0; h < 2; ++h) { \
                float4 v = A[kst][h]; \
                float4 g = G[kst][h], bb = Bb[kst][h]; \
                v.x = (v.x-mean)*rstd*g.x + bb.x; \
                v.y = (v.y-mean)*rstd*g.y + bb.y; \
                v.z = (v.z-mean)*rstd*g.z + bb.z; \
                v.w = (v.w-mean)*rstd*g.w + bb.w; \
                A[kst][h] = v; \
                s2 += v.x*v.x + v.y*v.y + v.z*v.z + v.w*v.w; \
            } \
        s2 += __shfl_xor(s2, 16); s2 += __shfl_xor(s2, 32); \
        float rl2 = 1.f / fmaxf(sqrtf(s2), 1e-12f); \
        _Pragma("unroll") \
        for (int kst = 0; kst < 4; ++kst) { \
            float4 va = A[kst][0], vb = A[kst][1]; \
            va.x*=rl2; va.y*=rl2; va.z*=rl2; va.w*=rl2; \
            vb.x*=rl2; vb.y*=rl2; vb.z*=rl2; vb.w*=rl2; \
            H8U4 h, lo; \
            h.h[0]=(_Float16)va.x; h.h[1]=(_Float16)va.y; h.h[2]=(_Float16)va.z; h.h[3]=(_Float16)va.w; \
            h.h[4]=(_Float16)vb.x; h.h[5]=(_Float16)vb.y; h.h[6]=(_Float16)vb.z; h.h[7]=(_Float16)vb.w; \
            lo.h[0]=(_Float16)(va.x-(float)h.h[0]); lo.h[1]=(_Float16)(va.y-(float)h.h[1]); \
            lo.h[2]=(_Float16)(va.z-(float)h.h[2]); lo.h[3]=(_Float16)(va.w-(float)h.h[3]); \
            lo.h[4]=(_Float16)(vb.x-(float)h.h[4]); lo.h[5]=(_Float16)(vb.y-(float)h.h[5]); \
            lo.h[6]=(_Float16)(vb.z-(float)h.h[6]); lo.h[7]=(_Float16)(vb.w-(float)h.h[7]); \
            fah[kst] = h.h; \
            fal[kst] = lo.h; \
        } \
    } while (0)

// staged GEMM over 7 stages (2-deep buffering; B_{s+1} issued at stage-s top)
#define GEMM_LOOP do { \
        _Pragma("unroll") \
        for (int nt = 0; nt < 13; ++nt) \
            acc[nt] = (f32x4){0.f,0.f,0.f,0.f}; \
        __syncthreads(); \
        _Pragma("unroll") \
        for (int s = 0; s < 7; ++s) { \
            if (s < 6) STAGE_B(s + 1, (s + 1) & 1); \
            const uint4* bb = bbuf + (s & 1)*1024; \
            if (s < 6) { \
                _Pragma("unroll") \
                for (int kst = 0; kst < 4; ++kst) { \
                    const int slz = (kst*4 + l4) ^ l15; \
                    half8 b0h = lds_h8(bb + l15*16 + slz); \
                    half8 b0l = lds_h8(bb + 512 + l15*16 + slz); \
                    half8 b1h = lds_h8(bb + (16+l15)*16 + slz); \
                    half8 b1l = lds_h8(bb + 512 + (16+l15)*16 + slz); \
                    acc[2*s]   = MFMA_(b0h, fah[kst], acc[2*s]); \
                    acc[2*s+1] = MFMA_(b1h, fah[kst], acc[2*s+1]); \
                    acc[2*s]   = MFMA_(b0h, fal[kst], acc[2*s]); \
                    acc[2*s+1] = MFMA_(b1h, fal[kst], acc[2*s+1]); \
                    acc[2*s]   = MFMA_(b0l, fah[kst], acc[2*s]); \
                    acc[2*s+1] = MFMA_(b1l, fah[kst], acc[2*s+1]); \
                    acc[2*s]   = MFMA_(b0l, fal[kst], acc[2*s]); \
                    acc[2*s+1] = MFMA_(b1l, fal[kst], acc[2*s+1]); \
                } \
            } else { \
                _Pragma("unroll") \
                for (int kst = 0; kst < 4; ++kst) { \
                    const int slz = (kst*4 + l4) ^ l15; \
                    half8 b0h = lds_h8(bb + l15*16 + slz); \
                    half8 b0l = lds_h8(bb + 512 + l15*16 + slz); \
                    acc[12] = MFMA_(b0h, fah[kst], acc[12]); \
                    acc[12] = MFMA_(b0h, fal[kst], acc[12]); \
                    acc[12] = MFMA_(b0l, fah[kst], acc[12]); \
                    acc[12] = MFMA_(b0l, fal[kst], acc[12]); \
                } \
            } \
            __syncthreads(); \
        } \
    } while (0)

#define EPI_WRITE do { \
        int row = (w & 1)*16 + l15; \
        _Pragma("unroll") \
        for (int nt = 0; nt < 13; ++nt) \
            if (nt < 12 || l4 < 2) { \
                float4 sv; \
                sv.x = acc[nt][0]; sv.y = acc[nt][1]; \
                sv.z = acc[nt][2]; sv.w = acc[nt][3]; \
                *reinterpret_cast<float4*>(&epi[row*EPIT + nt*16 + l4*4]) = sv; \
            } \
    } while (0)

#define PASS_COMPUTE(P) do { \
        { \
            float* pdst = plog + (size_t)(pbase + (P)*32)*200; \
            _Pragma("unroll") \
            for (int it = 0; it < 7; ++it) { \
                int f = it*256 + t; \
                if (f < 1600) { \
                    int row = f / 50, c4 = f - row*50; \
                    const float* sp = &epi[row*EPIT + c4*4]; \
                    nt_store4(&pdst[(size_t)f*4], sp[0], sp[1], sp[2], sp[3]); \
                } \
            } \
        } \
        if (t < 128) { \
            const int q = t >> 2, sub = t & 3; \
            const int n = pbase + (P)*32 + q; \
            float ml[5]; \
            _Pragma("unroll") \
            for (int kk = 0; kk < 5; ++kk) { \
                int k = sub*5 + kk; \
                float mx = epi[q*EPIT + k*10]; \
                _Pragma("unroll") \
                for (int m = 1; m < 10; ++m) mx = fmaxf(mx, epi[q*EPIT + k*10 + m]); \
                ml[kk] = mx; \
            } \
            float s0 = ml[0]+ml[1]+ml[2]+ml[3]+ml[4]; \
            s0 += __shfl_xor(s0,1); s0 += __shfl_xor(s0,2); \
            float mean = s0 / 20.f; \
            float s1 = 0.f; \
            _Pragma("unroll") \
            for (int kk = 0; kk < 5; ++kk) { float d = ml[kk]-mean; s1 += d*d; } \
            s1 += __shfl_xor(s1,1); s1 += __shfl_xor(s1,2); \
            float rstd = rsqrtf(s1 / 20.f + LNEPS); \
            float bv = -1e30f; int bk = 0; \
            _Pragma("unroll") \
            for (int kk = 0; kk < 5; ++kk) { \
                int k = sub*5 + kk; \
                float y = (ml[kk]-mean)*rstd*mg[k] + mb[k]; \
                osg[q*20 + k] = y; \
                if (y > bv) { bv = y; bk = k; } \
            } \
            _Pragma("unroll") \
            for (int off = 1; off <= 2; off <<= 1) { \
                float ov = __shfl_xor(bv, off); \
                int   ok = __shfl_xor(bk, off); \
                if (ov > bv || (ov == bv && ok < bk)) { bv = ov; bk = ok; } \
            } \
            int g = gt[n]; \
            if (sub == 0) { \
                if (bk == g) { \
                    int slot = atomicAdd(ccnt, 1); \
                    if (slot < CCAP) cidx[slot] = n; \
                } \
                _Pragma("unroll") \
                for (int m = 0; m < 10; ++m) \
                    exs[q*10 + m] = expf(epi[q*EPIT + g*10 + m] / EPSI); \
                gtS[(P)*32 + q] = g; \
            } \
        } \
    } while (0)

#define PASS_STORE(P) do { \
        if (t < 160) { \
            const float* sp = &osg[t*4]; \
            nt_store4(&out_seg[(size_t)(pbase + (P)*32)*20 + t*4], sp[0], sp[1], sp[2], sp[3]); \
        } else if (t < 240) { \
            int f = t - 160; \
            *reinterpret_cast<float4*>(&expv[(size_t)(pbase + (P)*32)*10 + f*4]) \
                = *reinterpret_cast<const float4*>(&exs[f*4]); \
        } \
        if (t < 200) { \
            int kk = t / 10, mm = t - kk*10; \
            _Pragma("unroll 4") \
            for (int i = 0; i < 32; ++i) \
                if (gtS[(P)*32 + i] == kk) eacc += exs[i*10 + mm]; \
        } \
    } while (0)

    float4 A[4][2];
    half8 fah[4], fal[4];
    f32x4 acc[13];
    float eacc = 0.f, ccum = 0.f;
    int pbase = blk * 128;

    // ================= chunk 0 =================
    STAGE_B(0, 0);
    STAGE_B(1, 1);
    ALOAD(pbase);
    LN_BODY;
    GEMM_LOOP;

    // prefetch chunk-1 A into (dead) A registers — hidden under epilogue
    ALOAD(pbase + 64);

    // epilogue chunk 0
    if ((w >> 1) == 0) EPI_WRITE;
    __syncthreads();                 // epi p0 visible
    PASS_COMPUTE(0);
    __syncthreads();                 // epi p0 reads done; osg/exs p0 visible
    PASS_STORE(0);
    if ((w >> 1) == 1) EPI_WRITE;
    __syncthreads();                 // epi p1 visible; osg/exs p0 reads done
    PASS_COMPUTE(1);
    __syncthreads();                 // osg/exs p1 visible; all epi reads done
    PASS_STORE(1);
    STAGE_B(0, 0);                   // chunk-1 B0 into buf0 ([0,16K): epi-dead)
    if (t < 160) {                   // class counts chunk 0
        int c = t >> 3, o = t & 7;
        float cnt = 0.f;
        for (int i = o*8; i < o*8 + 8; ++i)
            if (gtS[i] == c) cnt += 1.f;
        part[t] = cnt;
    }
    __syncthreads();                 // part visible; osg/exs reads done
    if (t < 20) {
        float cnt = 0.f;
        #pragma unroll
        for (int o = 0; o < 8; ++o) cnt += part[t*8+o];
        ccum += cnt;
    }
    __syncthreads();                 // buf1 region ([16K,32K)) now dead

    // ================= chunk 1 =================
    pbase += 64;
    STAGE_B(1, 1);
    LN_BODY;                         // A already in regs (prefetched)
    GEMM_LOOP;

    // epilogue chunk 1
    if ((w >> 1) == 0) EPI_WRITE;
    __syncthreads();
    PASS_COMPUTE(0);
    __syncthreads();
    PASS_STORE(0);
    if ((w >> 1) == 1) EPI_WRITE;
    __syncthreads();
    PASS_COMPUTE(1);
    __syncthreads();
    PASS_STORE(1);
    if (t < 160) {
        int c = t >> 3, o = t & 7;
        float cnt = 0.f;
        for (int i = o*8; i < o*8 + 8; ++i)
            if (gtS[i] == c) cnt += 1.f;
        part[t] = cnt;
    }
    __syncthreads();
    if (t < 20) {
        float cnt = 0.f;
        #pragma unroll
        for (int o = 0; o < 8; ++o) cnt += part[t*8+o];
        cntS[t] = ccum + cnt;
    }
    __syncthreads();
    // ---- ONE coalesced 224-float record per block (128 points)
    if (t < 224)
        pcb[(size_t)blk*224 + t] = (t < 200) ? eacc : ((t < 220) ? cntS[t-200] : 0.f);
#undef STAGE_B
#undef ALOAD
#undef LN_BODY
#undef GEMM_LOOP
#undef EPI_WRITE
#undef PASS_COMPUTE
#undef PASS_STORE
}

// ---- per-column reduce of pcb (2048 records) -> colsum[220]. Grid 220.
__global__ __launch_bounds__(256) void k_red1a(
    const float* __restrict__ pcb, float* __restrict__ colsum)
{
    __shared__ float red[256];
    int t = threadIdx.x, col = blockIdx.x;
    float s = 0.f;
    #pragma unroll
    for (int i = 0; i < 8; ++i) s += pcb[(size_t)(i*256 + t)*224 + col];
    red[t] = s; __syncthreads();
    for (int off = 128; off > 0; off >>= 1) { if (t < off) red[t] += red[t+off]; __syncthreads(); }
    if (t == 0) colsum[col] = red[0];
}

// ---- sinkhorn row pass with fused v-chain (iter = 2,3).
__global__ __launch_bounds__(256) void k_row(int iter,
    const int* __restrict__ gt, const float* __restrict__ expv,
    const float* __restrict__ uh, const float* __restrict__ cs,
    float* __restrict__ pr)
{
    __shared__ float prodS[2560];
    __shared__ int gtS[256];
    __shared__ float uS[200], skS[20], BcS[20];
    int t = threadIdx.x, b = blockIdx.x;
    if (t < 20) {
        skS[t] = class_S(cs, t);
        BcS[t] = cs[200 + t];
    }
    if (t < 200) uS[t] = u1_of(cs, t);
    int n = b*256 + t;
    int g = gt[n];
    float e[10];
    {
        const float2* e2 = (const float2*)(expv + (size_t)n*10);
        float2 a0=e2[0], a1=e2[1], a2=e2[2], a3=e2[3], a4=e2[4];
        e[0]=a0.x; e[1]=a0.y; e[2]=a1.x; e[3]=a1.y; e[4]=a2.x;
        e[5]=a2.y; e[6]=a3.x; e[7]=a3.y; e[8]=a4.x; e[9]=a4.y;
    }
    __syncthreads();
    float skg = skS[g];
    float v = (skg > 0.f) ? 1.f/skg : 1.f;
    float B = BcS[g];
    float Bs = (B > 0.f) ? B : 1.f;
    {   // c = 1 uses u1 (from colsum)
        const float* uc = &uS[g*10];
        float sc = 0.f;
        #pragma unroll
        for (int m = 0; m < 10; ++m) sc += e[m]*uc[m];
        v = (sc > 0.f) ? 1.f/(Bs*sc) : v/Bs;
    }
    if (iter == 3) {   // c = 2 uses u2 (global uh[200..])
        const float* uc = uh + 200 + g*10;
        float sc = 0.f;
        #pragma unroll
        for (int m = 0; m < 10; ++m) sc += e[m]*uc[m];
        v = (sc > 0.f) ? 1.f/(Bs*sc) : v/Bs;
    }
    #pragma unroll
    for (int m = 0; m < 10; ++m) prodS[t*10+m] = e[m]*v;
    gtS[t] = g;
    __syncthreads();
    if (t < 200) {
        int kk = t / 10, mm = t % 10;
        float acc = 0.f;
        for (int i = 0; i < 256; ++i)
            if (gtS[i] == kk) acc += prodS[i*10+mm];
        pr[(size_t)t*1024 + b] = acc;
    }
}

// ---- row partials -> u_hist[iter] (faithful rs>0 guard), deterministic.
__global__ __launch_bounds__(256) void k_reduce_u(int iter,
    const float* __restrict__ pr, const float* __restrict__ cs,
    float* __restrict__ uh)
{
    __shared__ float red[256];
    int t = threadIdx.x, j = blockIdx.x;
    float s = 0.f;
    #pragma unroll
    for (int i = 0; i < 4; ++i) s += pr[(size_t)j*1024 + i*256 + t];
    red[t] = s; __syncthreads();
    for (int off = 128; off > 0; off >>= 1) { if (t < off) red[t] += red[t+off]; __syncthreads(); }
    if (t == 0) {
        float S = red[0];
        float uprev = (iter == 2) ? u1_of(cs, j) : uh[(iter-2)*200 + j];
        uh[(iter-1)*200 + j] = (S > 0.f) ? 1.f/(10.f*S) : uprev*0.1f;
    }
}

// ---- assignment + f/ncount accumulation
__global__ __launch_bounds__(256) void k_post(
    const int* __restrict__ gt, const float* __restrict__ expv,
    const float* __restrict__ u,
    const int* __restrict__ cidx, const int* __restrict__ ccnt,
    const float* __restrict__ feat, const float* __restrict__ fg,
    const float* __restrict__ fb,
    float* __restrict__ ptarget, float* __restrict__ facc,
    float* __restrict__ ncount)
{
    int t = threadIdx.x;
    {
        int n = blockIdx.x*256 + t;
        int g = gt[n];
        const float* uk = u + g*10;
        const float2* e2 = (const float2*)(expv + (size_t)n*10);
        float bv = -1e30f; int idx = 0;
        #pragma unroll
        for (int m2 = 0; m2 < 5; ++m2) {
            float2 ev = e2[m2];
            float p0 = ev.x * uk[m2*2], p1 = ev.y * uk[m2*2+1];
            if (p0 > bv) { bv = p0; idx = m2*2; }
            if (p1 > bv) { bv = p1; idx = m2*2+1; }
        }
        ptarget[n] = (float)(idx + 10*g);
    }
    int wid = blockIdx.x*4 + (t >> 6);
    int lane = t & 63;
    int cnt = *ccnt; if (cnt > CCAP) cnt = CCAP;
    for (int i = wid; i < cnt; i += 4096) {
        int n = cidx[i];
        float x0 = feat[(size_t)n*128 + lane], x1 = feat[(size_t)n*128 + 64 + lane];
        float s = x0 + x1;
        #pragma unroll
        for (int off = 32; off > 0; off >>= 1) s += __shfl_xor(s, off);
        float mean = s * (1.f/128.f);
        float d0 = x0 - mean, d1 = x1 - mean;
        float s2 = d0*d0 + d1*d1;
        #pragma unroll
        for (int off = 32; off > 0; off >>= 1) s2 += __shfl_xor(s2, off);
        float rstd = rsqrtf(s2 * (1.f/128.f) + LNEPS);
        float y0 = d0*rstd*fg[lane] + fb[lane];
        float y1 = d1*rstd*fg[64+lane] + fb[64+lane];
        float s3 = y0*y0 + y1*y1;
        #pragma unroll
        for (int off = 32; off > 0; off >>= 1) s3 += __shfl_xor(s3, off);
        float rl2 = 1.f / fmaxf(sqrtf(s3), 1e-12f);
        float c0 = y0*rl2, c1 = y1*rl2;
        int g = gt[n];
        const float* uk = u + g*10;
        const float2* e2 = (const float2*)(expv + (size_t)n*10);
        float bv = -1e30f; int idx = 0;
        #pragma unroll
        for (int m2 = 0; m2 < 5; ++m2) {
            float2 ev = e2[m2];
            float p0 = ev.x * uk[m2*2], p1 = ev.y * uk[m2*2+1];
            if (p0 > bv) { bv = p0; idx = m2*2; }
            if (p1 > bv) { bv = p1; idx = m2*2+1; }
        }
        float* frow = facc + (size_t)(g*10+idx)*128;
        atomicAdd(&frow[lane], c0);
        atomicAdd(&frow[64+lane], c1);
        if (lane == 0) atomicAdd(&ncount[g*10+idx], 1.f);
    }
}

// ---- momentum update + renormalize prototypes
__global__ __launch_bounds__(64) void k_proto_update(
    const float* __restrict__ facc, const float* __restrict__ ncount,
    const float* __restrict__ pn, float* __restrict__ outp)
{
    const float OMG = (float)(1.0 - 0.99);
    int j = blockIdx.x, l = threadIdx.x;
    float f0 = facc[(size_t)j*128+l], f1 = facc[(size_t)j*128+64+l];
    float ss = f0*f0 + f1*f1;
    #pragma unroll
    for (int off = 32; off > 0; off >>= 1) ss += __shfl_xor(ss, off);
    float fl2 = fmaxf(sqrtf(ss), 1e-12f);
    float fn0 = f0/fl2, fn1 = f1/fl2;
    float p0 = pn[(size_t)j*128+l], p1 = pn[(size_t)j*128+64+l];
    float u0 = 0.99f*p0 + OMG*fn0, u1 = 0.99f*p1 + OMG*fn1;
    bool ok = ncount[j] > 0.f;
    float s0 = ok ? u0 : p0, s1 = ok ? u1 : p1;
    float ss2 = s0*s0 + s1*s1;
    #pragma unroll
    for (int off = 32; off > 0; off >>= 1) ss2 += __shfl_xor(ss2, off);
    float l2 = fmaxf(sqrtf(ss2), 1e-12f);
    outp[(size_t)j*128+l]      = s0/l2;
    outp[(size_t)j*128+64+l]   = s1/l2;
}

extern "C" void kernel_launch(void* const* d_in, const int* in_sizes, int n_in,
                              void* d_out, int out_size, void* d_ws, size_t ws_size,
                              hipStream_t stream)
{
    const float* feat   = (const float*)d_in[0];
    const int*   gt     = (const int*)  d_in[1];
    const float* protos = (const float*)d_in[2];
    const float* fg     = (const float*)d_in[3];
    const float* fb     = (const float*)d_in[4];
    const float* mg     = (const float*)d_in[5];
    const float* mb     = (const float*)d_in[6];

    float* out      = (float*)d_out;
    float* out_seg  = out;
    float* plog     = out + (size_t)NPTS*20;
    float* ptarget  = out + (size_t)NPTS*220;
    float* newp     = out + (size_t)NPTS*221;

    float* ws   = (float*)d_ws;
    float* pn   = ws + WS_PN;
    _Float16* phi = (_Float16*)(ws + WS_PHI);
    _Float16* plo = (_Float16*)(ws + WS_PLO);
    float* facc = ws + WS_F;
    float* ncnt = ws + WS_NCOUNT;
    int*   ccnt = (int*)(ws + WS_CCNT);
    float* uh   = ws + WS_UH;
    float* cs   = ws + WS_CS;
    float* pcb  = ws + WS_PCB;
    float* pr   = ws + WS_PCB;       // aliases pcb (pcb consumed by k_red1a first)
    float* expv = ws + WS_EXPV;
    int*   cidx = (int*)(ws + WS_CIDX);

    // k_norm_protos also zeroes facc/ncnt/ccnt (contiguous from facc)
    hipLaunchKernelGGL(k_norm_protos, dim3(224), dim3(64), 0, stream,
                       protos, pn, phi, plo, facc);
    hipLaunchKernelGGL(k_main, dim3(2048), dim3(256), 0, stream,
                       feat, gt, phi, plo, fg, fb, mg, mb, out_seg, plog, expv, pcb,
                       cidx, ccnt);
    hipLaunchKernelGGL(k_red1a, dim3(220), dim3(256), 0, stream, pcb, cs);
    for (int it = 2; it <= 3; ++it) {
        hipLaunchKernelGGL(k_row, dim3(1024), dim3(256), 0, stream, it, gt, expv, uh, cs, pr);
        hipLaunchKernelGGL(k_reduce_u, dim3(200), dim3(256), 0, stream, it, pr, cs, uh);
    }
    hipLaunchKernelGGL(k_post, dim3(1024), dim3(256), 0, stream,
                       gt, expv, uh + 400, cidx, ccnt, feat, fg, fb, ptarget, facc, ncnt);
    hipLaunchKernelGGL(k_proto_update, dim3(200), dim3(64), 0, stream, facc, ncnt, pn, newp);
}

// Round 20
// 230.599 us; speedup vs baseline: 1.0869x; 1.0869x over previous
//
#include <hip/hip_runtime.h>
#include <hip/hip_bf16.h>

#define NPTS 262144
#define DIM  128
#define KC   20
#define MP   10
#define LNEPS 1e-5f
#define EPSI  0.05f
#define CCAP  65536

typedef _Float16 half8 __attribute__((ext_vector_type(8)));
typedef float f32x4 __attribute__((ext_vector_type(4)));
typedef float fv4 __attribute__((ext_vector_type(4)));

union H8U4 { half8 h; uint4 u; };

// workspace layout (float offsets)
#define WS_PN     0          // 25600 normalized protos f32
#define WS_PHI    25600      // 14336 floats (224x128 f16 hi, PRE-SWIZZLED, rows 200..223 zero)
#define WS_PLO    39936      // 14336 floats (f16 lo, PRE-SWIZZLED)
#define WS_F      54272      // 25600 f accumulator
#define WS_NCOUNT 79872      // 200
#define WS_CCNT   80072      // 8 ints (ccnt + pad)
#define WS_UH     80080      // 600 u history (3 x 200)
#define WS_CS     80680      // 224 column sums (0..199 e-sums, 200..219 counts)
#define WS_PCB    80904      // 4096*224 per-block partials (coalesced); pr aliases
#define WS_EXPV   998408     // N*10 packed
#define WS_CIDX   3619848    // 65536 ints
// total 3685384 floats = 14.7 MB

#define EPIT 212   // epilogue LDS pitch (16B-aligned rows)

#define MFMA_(b_, a_, c_) __builtin_amdgcn_mfma_f32_16x16x32_f16(b_, a_, c_, 0, 0, 0)

__device__ __forceinline__ half8 lds_h8(const uint4* p) {
    return *reinterpret_cast<const half8*>(p);
}

// async global->LDS, 16B per lane; LDS dest = wave-uniform base + lane*16
__device__ __forceinline__ void gload_lds16(const uint4* g, uint4* l) {
    __builtin_amdgcn_global_load_lds(
        (const __attribute__((address_space(1))) void*)(g),
        (__attribute__((address_space(3))) void*)(l), 16, 0, 0);
}

// nontemporal float4 store (final outputs: skip L2 retention)
__device__ __forceinline__ void nt_store4(float* p, float x, float y, float z, float w) {
    fv4 v = {x, y, z, w};
    __builtin_nontemporal_store(v, (fv4*)p);
}

// u1 / S from colsum — pure function, identical everywhere (left-assoc order)
__device__ __forceinline__ float class_S(const float* cs, int k) {
    float S = 0.f;
    #pragma unroll
    for (int m = 0; m < 10; ++m) S += cs[k*10 + m];
    return S;
}
__device__ __forceinline__ float u1_of(const float* cs, int j) {
    int k = j / 10;
    float S = class_S(cs, k);
    float r1 = (S > 0.f) ? cs[j] / S : cs[j];
    return (r1 > 0.f) ? 1.f/(10.f*r1) : 0.1f;
}

// ---- normalize prototypes; emit f32 (pn) + PRE-SWIZZLED f16 hi/lo.
//  Also zeroes the facc/ncount/ccnt region (folds the memset launch).
__global__ __launch_bounds__(64) void k_norm_protos(
    const float* __restrict__ pr, float* __restrict__ pn,
    _Float16* __restrict__ phi, _Float16* __restrict__ plo,
    float* __restrict__ zbuf)
{
    int j = blockIdx.x, l = threadIdx.x;
    {   // grid-stride zero of facc(25600)+ncnt(200)+ccnt(8) = 25808 floats
        int tid = j*64 + l;
        for (int i = tid; i < 25808; i += 14336) zbuf[i] = 0.f;
    }
    const int jm = j & 15;
    const int s1 = l >> 3,       swz1 = (((s1 ^ jm) << 3) | (l & 7));
    const int s2 = 8 + (l >> 3), swz2 = (((s2 ^ jm) << 3) | (l & 7));
    if (j < 200) {
        float x0 = pr[(size_t)j*128 + l], x1 = pr[(size_t)j*128 + 64 + l];
        float ss = x0*x0 + x1*x1;
        #pragma unroll
        for (int off = 32; off > 0; off >>= 1) ss += __shfl_xor(ss, off);
        float dn = fmaxf(sqrtf(ss), 1e-12f);
        float y0 = x0/dn, y1 = x1/dn;
        pn[(size_t)j*128 + l]      = y0;
        pn[(size_t)j*128 + 64 + l] = y1;
        _Float16 h0 = (_Float16)y0, h1 = (_Float16)y1;
        phi[(size_t)j*128 + swz1] = h0;
        phi[(size_t)j*128 + swz2] = h1;
        plo[(size_t)j*128 + swz1] = (_Float16)(y0 - (float)h0);
        plo[(size_t)j*128 + swz2] = (_Float16)(y1 - (float)h1);
    } else {
        phi[(size_t)j*128 + swz1] = (_Float16)0.f;  phi[(size_t)j*128 + swz2] = (_Float16)0.f;
        plo[(size_t)j*128 + swz1] = (_Float16)0.f;  plo[(size_t)j*128 + swz2] = (_Float16)0.f;
    }
}

// ---- main kernel: 4096 blocks x 256 thr (4 waves), 64 pts/block.
//  Epilogue restructured to 6 barriers: stores/eacc of pass p share a phase
//  with pass p+1's epi-write (disjoint LDS regions).
__global__ __launch_bounds__(256, 4) void k_main(
    const float* __restrict__ feat, const int* __restrict__ gt,
    const _Float16* __restrict__ phi, const _Float16* __restrict__ plo,
    const float* __restrict__ fg, const float* __restrict__ fb,
    const float* __restrict__ mg, const float* __restrict__ mb,
    float* __restrict__ out_seg, float* __restrict__ plog,
    float* __restrict__ expv, float* __restrict__ pcb,
    int* __restrict__ cidx, int* __restrict__ ccnt)
{
    __shared__ __align__(16) char ldsb[32768];
    uint4* bbuf = (uint4*)ldsb;                  // 2 bufs x 1024 u4 (32768 B); GEMM phase
    float* epi  = (float*)ldsb;                  // [32][EPIT] = 27136 B; epilogue phase
    float* osg  = (float*)(ldsb + 27136);        // [32][20] = 2560 B
    float* exs  = (float*)(ldsb + 29696);        // [32][10] = 1280 B
    int*   gtS  = (int*)  (ldsb + 30976);        // 64 ints
    float* part = (float*)(ldsb + 31232);        // 160 floats
    float* cntS = (float*)(ldsb + 31872);        // 20 floats -> ends 31952

    const int t = threadIdx.x, blk = blockIdx.x;
    const int w = t >> 6, lane = t & 63;
    const int l15 = lane & 15, l4 = lane >> 4;
    const int pbase = blk * 64;

    const uint4* phi4 = (const uint4*)phi;
    const uint4* plo4 = (const uint4*)plo;

#define STAGE_B(S, BI) do { \
        const uint4* gh = phi4 + (size_t)(S)*512 + t; \
        const uint4* gl = plo4 + (size_t)(S)*512 + t; \
        uint4* dh = bbuf + (BI)*1024 + w*64; \
        uint4* dl = bbuf + (BI)*1024 + 512 + w*64; \
        gload_lds16(gh,       dh); \
        gload_lds16(gh + 256, dh + 256); \
        gload_lds16(gl,       dl); \
        gload_lds16(gl + 256, dl + 256); \
    } while (0)

// epi-write for pass P (executed by waves (w>>1)==P)
#define EPI_WRITE(P) do { \
        int row = (w & 1)*16 + l15; \
        _Pragma("unroll") \
        for (int nt = 0; nt < 13; ++nt) \
            if (nt < 12 || l4 < 2) { \
                float4 sv; \
                sv.x = acc[nt][0]; sv.y = acc[nt][1]; \
                sv.z = acc[nt][2]; sv.w = acc[nt][3]; \
                *reinterpret_cast<float4*>(&epi[row*EPIT + nt*16 + l4*4]) = sv; \
            } \
    } while (0)

// plog stream + LN/argmax/exp compute for pass P
#define PASS_COMPUTE(P) do { \
        { \
            float* pdst = plog + (size_t)(pbase + (P)*32)*200; \
            _Pragma("unroll") \
            for (int it = 0; it < 7; ++it) { \
                int f = it*256 + t; \
                if (f < 1600) { \
                    int row = f / 50, c4 = f - row*50; \
                    const float* sp = &epi[row*EPIT + c4*4]; \
                    nt_store4(&pdst[(size_t)f*4], sp[0], sp[1], sp[2], sp[3]); \
                } \
            } \
        } \
        if (t < 128) { \
            const int q = t >> 2, sub = t & 3; \
            const int n = pbase + (P)*32 + q; \
            float ml[5]; \
            _Pragma("unroll") \
            for (int kk = 0; kk < 5; ++kk) { \
                int k = sub*5 + kk; \
                float mx = epi[q*EPIT + k*10]; \
                _Pragma("unroll") \
                for (int m = 1; m < 10; ++m) mx = fmaxf(mx, epi[q*EPIT + k*10 + m]); \
                ml[kk] = mx; \
            } \
            float s0 = ml[0]+ml[1]+ml[2]+ml[3]+ml[4]; \
            s0 += __shfl_xor(s0,1); s0 += __shfl_xor(s0,2); \
            float mean = s0 / 20.f; \
            float s1 = 0.f; \
            _Pragma("unroll") \
            for (int kk = 0; kk < 5; ++kk) { float d = ml[kk]-mean; s1 += d*d; } \
            s1 += __shfl_xor(s1,1); s1 += __shfl_xor(s1,2); \
            float rstd = rsqrtf(s1 / 20.f + LNEPS); \
            float bv = -1e30f; int bk = 0; \
            _Pragma("unroll") \
            for (int kk = 0; kk < 5; ++kk) { \
                int k = sub*5 + kk; \
                float y = (ml[kk]-mean)*rstd*mg[k] + mb[k]; \
                osg[q*20 + k] = y; \
                if (y > bv) { bv = y; bk = k; } \
            } \
            _Pragma("unroll") \
            for (int off = 1; off <= 2; off <<= 1) { \
                float ov = __shfl_xor(bv, off); \
                int   ok = __shfl_xor(bk, off); \
                if (ov > bv || (ov == bv && ok < bk)) { bv = ov; bk = ok; } \
            } \
            int g = gt[n]; \
            if (sub == 0) { \
                if (bk == g) { \
                    int slot = atomicAdd(ccnt, 1); \
                    if (slot < CCAP) cidx[slot] = n; \
                } \
                _Pragma("unroll") \
                for (int m = 0; m < 10; ++m) \
                    exs[q*10 + m] = expf(epi[q*EPIT + g*10 + m] / EPSI); \
                gtS[(P)*32 + q] = g; \
            } \
        } \
    } while (0)

// stores + eacc for pass P
#define PASS_STORE(P) do { \
        if (t < 160) { \
            const float* sp = &osg[t*4]; \
            nt_store4(&out_seg[(size_t)(pbase + (P)*32)*20 + t*4], sp[0], sp[1], sp[2], sp[3]); \
        } else if (t < 240) { \
            int f = t - 160; \
            *reinterpret_cast<float4*>(&expv[(size_t)(pbase + (P)*32)*10 + f*4]) \
                = *reinterpret_cast<const float4*>(&exs[f*4]); \
        } \
        if (t < 200) { \
            int kk = t / 10, mm = t - kk*10; \
            _Pragma("unroll 4") \
            for (int i = 0; i < 32; ++i) \
                if (gtS[(P)*32 + i] == kk) eacc += exs[i*10 + mm]; \
        } \
    } while (0)

    STAGE_B(0, 0);

    // ---- A direct loads in fragment layout: row = pbase + w*16 + l15
    const float4* gfeat = (const float4*)feat;
    float4 A[4][2];
    {
        size_t rb = (size_t)(pbase + w*16 + l15) * 32;
        #pragma unroll
        for (int kst = 0; kst < 4; ++kst)
            #pragma unroll
            for (int h = 0; h < 2; ++h)
                A[kst][h] = gfeat[rb + kst*8 + l4*2 + h];
    }
    float4 G[4][2], Bb[4][2];
    {
        const float4* fg4 = (const float4*)fg;
        const float4* fb4 = (const float4*)fb;
        #pragma unroll
        for (int kst = 0; kst < 4; ++kst)
            #pragma unroll
            for (int h = 0; h < 2; ++h) {
                G[kst][h]  = fg4[kst*8 + l4*2 + h];
                Bb[kst][h] = fb4[kst*8 + l4*2 + h];
            }
    }

    // ---- LN + l2n (4-lane group reduce over lanes {l15,+16,+32,+48})
    half8 fah[4], fal[4];
    {
        float s0 = 0.f;
        #pragma unroll
        for (int kst = 0; kst < 4; ++kst)
            #pragma unroll
            for (int h = 0; h < 2; ++h) {
                float4 v = A[kst][h];
                s0 += v.x + v.y + v.z + v.w;
            }
        s0 += __shfl_xor(s0, 16); s0 += __shfl_xor(s0, 32);
        float mean = s0 * (1.f/128.f);
        float s1 = 0.f;
        #pragma unroll
        for (int kst = 0; kst < 4; ++kst)
            #pragma unroll
            for (int h = 0; h < 2; ++h) {
                float4 v = A[kst][h];
                float a = v.x-mean, b = v.y-mean, c = v.z-mean, d = v.w-mean;
                s1 += a*a + b*b + c*c + d*d;
            }
        s1 += __shfl_xor(s1, 16); s1 += __shfl_xor(s1, 32);
        float rstd = rsqrtf(s1 * (1.f/128.f) + LNEPS);
        float s2 = 0.f;
        #pragma unroll
        for (int kst = 0; kst < 4; ++kst)
            #pragma unroll
            for (int h = 0; h < 2; ++h) {
                float4 v = A[kst][h];
                float4 g = G[kst][h], bb = Bb[kst][h];
                v.x = (v.x-mean)*rstd*g.x + bb.x;
                v.y = (v.y-mean)*rstd*g.y + bb.y;
                v.z = (v.z-mean)*rstd*g.z + bb.z;
                v.w = (v.w-mean)*rstd*g.w + bb.w;
                A[kst][h] = v;
                s2 += v.x*v.x + v.y*v.y + v.z*v.z + v.w*v.w;
            }
        s2 += __shfl_xor(s2, 16); s2 += __shfl_xor(s2, 32);
        float rl2 = 1.f / fmaxf(sqrtf(s2), 1e-12f);
        #pragma unroll
        for (int kst = 0; kst < 4; ++kst) {
            float4 va = A[kst][0], vb = A[kst][1];
            va.x*=rl2; va.y*=rl2; va.z*=rl2; va.w*=rl2;
            vb.x*=rl2; vb.y*=rl2; vb.z*=rl2; vb.w*=rl2;
            H8U4 h, lo;
            h.h[0]=(_Float16)va.x; h.h[1]=(_Float16)va.y; h.h[2]=(_Float16)va.z; h.h[3]=(_Float16)va.w;
            h.h[4]=(_Float16)vb.x; h.h[5]=(_Float16)vb.y; h.h[6]=(_Float16)vb.z; h.h[7]=(_Float16)vb.w;
            lo.h[0]=(_Float16)(va.x-(float)h.h[0]); lo.h[1]=(_Float16)(va.y-(float)h.h[1]);
            lo.h[2]=(_Float16)(va.z-(float)h.h[2]); lo.h[3]=(_Float16)(va.w-(float)h.h[3]);
            lo.h[4]=(_Float16)(vb.x-(float)h.h[4]); lo.h[5]=(_Float16)(vb.y-(float)h.h[5]);
            lo.h[6]=(_Float16)(vb.z-(float)h.h[6]); lo.h[7]=(_Float16)(vb.w-(float)h.h[7]);
            fah[kst] = h.h;
            fal[kst] = lo.h;
        }
    }

    f32x4 acc[13];
    #pragma unroll
    for (int nt = 0; nt < 13; ++nt)
        acc[nt] = (f32x4){0.f,0.f,0.f,0.f};

    __syncthreads();   // drains B0 (covered by A-load + LN)

    // ---- staged GEMM: 2-deep; issue B_{s+1} at TOP of stage s
    #pragma unroll
    for (int s = 0; s < 7; ++s) {
        if (s < 6) STAGE_B(s + 1, (s + 1) & 1);
        const uint4* bb = bbuf + (s & 1)*1024;
        if (s < 6) {
            #pragma unroll
            for (int kst = 0; kst < 4; ++kst) {
                const int slz = (kst*4 + l4) ^ l15;
                half8 b0h = lds_h8(bb + l15*16 + slz);
                half8 b0l = lds_h8(bb + 512 + l15*16 + slz);
                half8 b1h = lds_h8(bb + (16+l15)*16 + slz);
                half8 b1l = lds_h8(bb + 512 + (16+l15)*16 + slz);
                acc[2*s]   = MFMA_(b0h, fah[kst], acc[2*s]);
                acc[2*s+1] = MFMA_(b1h, fah[kst], acc[2*s+1]);
                acc[2*s]   = MFMA_(b0h, fal[kst], acc[2*s]);
                acc[2*s+1] = MFMA_(b1h, fal[kst], acc[2*s+1]);
                acc[2*s]   = MFMA_(b0l, fah[kst], acc[2*s]);
                acc[2*s+1] = MFMA_(b1l, fah[kst], acc[2*s+1]);
                acc[2*s]   = MFMA_(b0l, fal[kst], acc[2*s]);
                acc[2*s+1] = MFMA_(b1l, fal[kst], acc[2*s+1]);
            }
        } else {
            #pragma unroll
            for (int kst = 0; kst < 4; ++kst) {
                const int slz = (kst*4 + l4) ^ l15;
                half8 b0h = lds_h8(bb + l15*16 + slz);
                half8 b0l = lds_h8(bb + 512 + l15*16 + slz);
                acc[12] = MFMA_(b0h, fah[kst], acc[12]);
                acc[12] = MFMA_(b0h, fal[kst], acc[12]);
                acc[12] = MFMA_(b0l, fah[kst], acc[12]);
                acc[12] = MFMA_(b0l, fal[kst], acc[12]);
            }
        }
        __syncthreads();
    }

    // ---- epilogue, 6 barriers total
    float eacc = 0.f;
    if ((w >> 1) == 0) EPI_WRITE(0);
    __syncthreads();                 // 1: epi p0 visible
    PASS_COMPUTE(0);
    __syncthreads();                 // 2: epi p0 reads done; osg/exs p0 visible
    PASS_STORE(0);
    if ((w >> 1) == 1) EPI_WRITE(1);
    __syncthreads();                 // 3: epi p1 visible; osg/exs p0 reads done
    PASS_COMPUTE(1);
    __syncthreads();                 // 4: osg/exs p1 visible; gtS complete
    PASS_STORE(1);
    // ---- per-block class counts (gtS complete since barrier 4)
    if (t < 160) {
        int c = t >> 3, o = t & 7;
        float cnt = 0.f;
        for (int i = o*8; i < o*8 + 8; ++i)
            if (gtS[i] == c) cnt += 1.f;
        part[t] = cnt;
    }
    __syncthreads();                 // 5: part visible
    if (t < 20) {
        float cnt = 0.f;
        #pragma unroll
        for (int o = 0; o < 8; ++o) cnt += part[t*8+o];
        cntS[t] = cnt;
    }
    __syncthreads();                 // 6: cntS visible
    // ---- ONE coalesced 224-float record per block
    if (t < 224)
        pcb[(size_t)blk*224 + t] = (t < 200) ? eacc : ((t < 220) ? cntS[t-200] : 0.f);
#undef STAGE_B
#undef EPI_WRITE
#undef PASS_COMPUTE
#undef PASS_STORE
}

// ---- per-column reduce of pcb -> colsum[220]. Grid 220 (one block per column)
__global__ __launch_bounds__(256) void k_red1a(
    const float* __restrict__ pcb, float* __restrict__ colsum)
{
    __shared__ float red[256];
    int t = threadIdx.x, col = blockIdx.x;
    float s = 0.f;
    #pragma unroll
    for (int i = 0; i < 16; ++i) s += pcb[(size_t)(i*256 + t)*224 + col];
    red[t] = s; __syncthreads();
    for (int off = 128; off > 0; off >>= 1) { if (t < off) red[t] += red[t+off]; __syncthreads(); }
    if (t == 0) colsum[col] = red[0];
}

// ---- sinkhorn row pass with fused v-chain (iter = 2,3).
__global__ __launch_bounds__(256) void k_row(int iter,
    const int* __restrict__ gt, const float* __restrict__ expv,
    const float* __restrict__ uh, const float* __restrict__ cs,
    float* __restrict__ pr)
{
    __shared__ float prodS[2560];
    __shared__ int gtS[256];
    __shared__ float uS[200], skS[20], BcS[20];
    int t = threadIdx.x, b = blockIdx.x;
    if (t < 20) {
        skS[t] = class_S(cs, t);
        BcS[t] = cs[200 + t];
    }
    if (t < 200) uS[t] = u1_of(cs, t);
    int n = b*256 + t;
    int g = gt[n];
    float e[10];
    {
        const float2* e2 = (const float2*)(expv + (size_t)n*10);
        float2 a0=e2[0], a1=e2[1], a2=e2[2], a3=e2[3], a4=e2[4];
        e[0]=a0.x; e[1]=a0.y; e[2]=a1.x; e[3]=a1.y; e[4]=a2.x;
        e[5]=a2.y; e[6]=a3.x; e[7]=a3.y; e[8]=a4.x; e[9]=a4.y;
    }
    __syncthreads();
    float skg = skS[g];
    float v = (skg > 0.f) ? 1.f/skg : 1.f;
    float B = BcS[g];
    float Bs = (B > 0.f) ? B : 1.f;
    {   // c = 1 uses u1 (from colsum)
        const float* uc = &uS[g*10];
        float sc = 0.f;
        #pragma unroll
        for (int m = 0; m < 10; ++m) sc += e[m]*uc[m];
        v = (sc > 0.f) ? 1.f/(Bs*sc) : v/Bs;
    }
    if (iter == 3) {   // c = 2 uses u2 (global uh[200..])
        const float* uc = uh + 200 + g*10;
        float sc = 0.f;
        #pragma unroll
        for (int m = 0; m < 10; ++m) sc += e[m]*uc[m];
        v = (sc > 0.f) ? 1.f/(Bs*sc) : v/Bs;
    }
    #pragma unroll
    for (int m = 0; m < 10; ++m) prodS[t*10+m] = e[m]*v;
    gtS[t] = g;
    __syncthreads();
    if (t < 200) {
        int kk = t / 10, mm = t % 10;
        float acc = 0.f;
        for (int i = 0; i < 256; ++i)
            if (gtS[i] == kk) acc += prodS[i*10+mm];
        pr[(size_t)t*1024 + b] = acc;
    }
}

// ---- row partials -> u_hist[iter] (faithful rs>0 guard), deterministic.
__global__ __launch_bounds__(256) void k_reduce_u(int iter,
    const float* __restrict__ pr, const float* __restrict__ cs,
    float* __restrict__ uh)
{
    __shared__ float red[256];
    int t = threadIdx.x, j = blockIdx.x;
    float s = 0.f;
    #pragma unroll
    for (int i = 0; i < 4; ++i) s += pr[(size_t)j*1024 + i*256 + t];
    red[t] = s; __syncthreads();
    for (int off = 128; off > 0; off >>= 1) { if (t < off) red[t] += red[t+off]; __syncthreads(); }
    if (t == 0) {
        float S = red[0];
        float uprev = (iter == 2) ? u1_of(cs, j) : uh[(iter-2)*200 + j];
        uh[(iter-1)*200 + j] = (S > 0.f) ? 1.f/(10.f*S) : uprev*0.1f;
    }
}

// ---- assignment + f/ncount accumulation
__global__ __launch_bounds__(256) void k_post(
    const int* __restrict__ gt, const float* __restrict__ expv,
    const float* __restrict__ u,
    const int* __restrict__ cidx, const int* __restrict__ ccnt,
    const float* __restrict__ feat, const float* __restrict__ fg,
    const float* __restrict__ fb,
    float* __restrict__ ptarget, float* __restrict__ facc,
    float* __restrict__ ncount)
{
    int t = threadIdx.x;
    {
        int n = blockIdx.x*256 + t;
        int g = gt[n];
        const float* uk = u + g*10;
        const float2* e2 = (const float2*)(expv + (size_t)n*10);
        float bv = -1e30f; int idx = 0;
        #pragma unroll
        for (int m2 = 0; m2 < 5; ++m2) {
            float2 ev = e2[m2];
            float p0 = ev.x * uk[m2*2], p1 = ev.y * uk[m2*2+1];
            if (p0 > bv) { bv = p0; idx = m2*2; }
            if (p1 > bv) { bv = p1; idx = m2*2+1; }
        }
        ptarget[n] = (float)(idx + 10*g);
    }
    int wid = blockIdx.x*4 + (t >> 6);
    int lane = t & 63;
    int cnt = *ccnt; if (cnt > CCAP) cnt = CCAP;
    for (int i = wid; i < cnt; i += 4096) {
        int n = cidx[i];
        float x0 = feat[(size_t)n*128 + lane], x1 = feat[(size_t)n*128 + 64 + lane];
        float s = x0 + x1;
        #pragma unroll
        for (int off = 32; off > 0; off >>= 1) s += __shfl_xor(s, off);
        float mean = s * (1.f/128.f);
        float d0 = x0 - mean, d1 = x1 - mean;
        float s2 = d0*d0 + d1*d1;
        #pragma unroll
        for (int off = 32; off > 0; off >>= 1) s2 += __shfl_xor(s2, off);
        float rstd = rsqrtf(s2 * (1.f/128.f) + LNEPS);
        float y0 = d0*rstd*fg[lane] + fb[lane];
        float y1 = d1*rstd*fg[64+lane] + fb[64+lane];
        float s3 = y0*y0 + y1*y1;
        #pragma unroll
        for (int off = 32; off > 0; off >>= 1) s3 += __shfl_xor(s3, off);
        float rl2 = 1.f / fmaxf(sqrtf(s3), 1e-12f);
        float c0 = y0*rl2, c1 = y1*rl2;
        int g = gt[n];
        const float* uk = u + g*10;
        const float2* e2 = (const float2*)(expv + (size_t)n*10);
        float bv = -1e30f; int idx = 0;
        #pragma unroll
        for (int m2 = 0; m2 < 5; ++m2) {
            float2 ev = e2[m2];
            float p0 = ev.x * uk[m2*2], p1 = ev.y * uk[m2*2+1];
            if (p0 > bv) { bv = p0; idx = m2*2; }
            if (p1 > bv) { bv = p1; idx = m2*2+1; }
        }
        float* frow = facc + (size_t)(g*10+idx)*128;
        atomicAdd(&frow[lane], c0);
        atomicAdd(&frow[64+lane], c1);
        if (lane == 0) atomicAdd(&ncount[g*10+idx], 1.f);
    }
}

// ---- momentum update + renormalize prototypes
__global__ __launch_bounds__(64) void k_proto_update(
    const float* __restrict__ facc, const float* __restrict__ ncount,
    const float* __restrict__ pn, float* __restrict__ outp)
{
    const float OMG = (float)(1.0 - 0.99);
    int j = blockIdx.x, l = threadIdx.x;
    float f0 = facc[(size_t)j*128+l], f1 = facc[(size_t)j*128+64+l];
    float ss = f0*f0 + f1*f1;
    #pragma unroll
    for (int off = 32; off > 0; off >>= 1) ss += __shfl_xor(ss, off);
    float fl2 = fmaxf(sqrtf(ss), 1e-12f);
    float fn0 = f0/fl2, fn1 = f1/fl2;
    float p0 = pn[(size_t)j*128+l], p1 = pn[(size_t)j*128+64+l];
    float u0 = 0.99f*p0 + OMG*fn0, u1 = 0.99f*p1 + OMG*fn1;
    bool ok = ncount[j] > 0.f;
    float s0 = ok ? u0 : p0, s1 = ok ? u1 : p1;
    float ss2 = s0*s0 + s1*s1;
    #pragma unroll
    for (int off = 32; off > 0; off >>= 1) ss2 += __shfl_xor(ss2, off);
    float l2 = fmaxf(sqrtf(ss2), 1e-12f);
    outp[(size_t)j*128+l]      = s0/l2;
    outp[(size_t)j*128+64+l]   = s1/l2;
}

extern "C" void kernel_launch(void* const* d_in, const int* in_sizes, int n_in,
                              void* d_out, int out_size, void* d_ws, size_t ws_size,
                              hipStream_t stream)
{
    const float* feat   = (const float*)d_in[0];
    const int*   gt     = (const int*)  d_in[1];
    const float* protos = (const float*)d_in[2];
    const float* fg     = (const float*)d_in[3];
    const float* fb     = (const float*)d_in[4];
    const float* mg     = (const float*)d_in[5];
    const float* mb     = (const float*)d_in[6];

    float* out      = (float*)d_out;
    float* out_seg  = out;
    float* plog     = out + (size_t)NPTS*20;
    float* ptarget  = out + (size_t)NPTS*220;
    float* newp     = out + (size_t)NPTS*221;

    float* ws   = (float*)d_ws;
    float* pn   = ws + WS_PN;
    _Float16* phi = (_Float16*)(ws + WS_PHI);
    _Float16* plo = (_Float16*)(ws + WS_PLO);
    float* facc = ws + WS_F;
    float* ncnt = ws + WS_NCOUNT;
    int*   ccnt = (int*)(ws + WS_CCNT);
    float* uh   = ws + WS_UH;
    float* cs   = ws + WS_CS;
    float* pcb  = ws + WS_PCB;
    float* pr   = ws + WS_PCB;       // aliases pcb (pcb consumed by k_red1a first)
    float* expv = ws + WS_EXPV;
    int*   cidx = (int*)(ws + WS_CIDX);

    // k_norm_protos also zeroes facc/ncnt/ccnt (contiguous from facc)
    hipLaunchKernelGGL(k_norm_protos, dim3(224), dim3(64), 0, stream,
                       protos, pn, phi, plo, facc);
    hipLaunchKernelGGL(k_main, dim3(4096), dim3(256), 0, stream,
                       feat, gt, phi, plo, fg, fb, mg, mb, out_seg, plog, expv, pcb,
                       cidx, ccnt);
    hipLaunchKernelGGL(k_red1a, dim3(220), dim3(256), 0, stream, pcb, cs);
    for (int it = 2; it <= 3; ++it) {
        hipLaunchKernelGGL(k_row, dim3(1024), dim3(256), 0, stream, it, gt, expv, uh, cs, pr);
        hipLaunchKernelGGL(k_reduce_u, dim3(200), dim3(256), 0, stream, it, pr, cs, uh);
    }
    hipLaunchKernelGGL(k_post, dim3(1024), dim3(256), 0, stream,
                       gt, expv, uh + 400, cidx, ccnt, feat, fg, fb, ptarget, facc, ncnt);
    hipLaunchKernelGGL(k_proto_update, dim3(200), dim3(64), 0, stream, facc, ncnt, pn, newp);
}